// Round 1
// baseline (2158.904 us; speedup 1.0000x reference)
//
#include <hip/hip_runtime.h>
#include <math.h>

#define BSZ 4
#define NH 16
#define SEQ 1024
#define DKH 64
#define ROWS 16
#define NTHR 256
#define QSTRIDE 68     // 68%32=4 -> rows hit distinct banks; 68*4%16==0 -> b128-able
#define HSTRIDE 1032   // halfs; 1032*2=2064 bytes, %16==0; word stride 516%32=4 -> no row conflicts

typedef _Float16 h4v __attribute__((ext_vector_type(4)));
typedef _Float16 h8v __attribute__((ext_vector_type(8)));

__global__ __launch_bounds__(NTHR, 4)
void fused_attn_kernel(const float* __restrict__ q,
                       const float* __restrict__ kk,
                       const float* __restrict__ v,
                       const float* __restrict__ prev,
                       const float* __restrict__ mask,
                       const unsigned char* __restrict__ kpm,
                       const float* __restrict__ scale_p,
                       float* __restrict__ out,
                       float* __restrict__ attn,
                       float* __restrict__ scores)
{
    __shared__ float    q_lds[ROWS][QSTRIDE];
    __shared__ _Float16 a_lds[ROWS][HSTRIDE];

    const int t     = threadIdx.x;
    const int r     = t >> 4;       // local row 0..15
    const int l16   = t & 15;       // lane within row group
    const int bh    = blockIdx.y;   // 0..63
    const int b     = bh >> 4;
    const int rt    = blockIdx.x;   // 0..63 row tile
    const int row_g = rt * ROWS + r;

    const float scale = *scale_p;

    // stage Q tile: contiguous 4KB, one float4 per thread
    {
        const float4* qsrc = (const float4*)(q + ((size_t)bh * SEQ + (size_t)rt * ROWS) * DKH);
        float4 qv = qsrc[t];
        *(float4*)&q_lds[t >> 4][(t & 15) * 4] = qv;
    }
    __syncthreads();

    const float* kbase = kk   + (size_t)bh * DKH * SEQ;                  // [64][1024]
    const float* prow  = prev + ((size_t)bh * SEQ + row_g) * SEQ;
    const float* mrow  = mask + (size_t)row_g * SEQ;                     // mask is [1][S][S]
    const unsigned char* kpmb = kpm + (size_t)b * SEQ;
    float* srow = scores + ((size_t)bh * SEQ + row_g) * SEQ;
    float* arow = attn   + ((size_t)bh * SEQ + row_g) * SEQ;

    // ---- phase 1: scores = q@k*scale + prev + mask (+kpm -inf); running row max ----
    float mx = -INFINITY;
    #pragma unroll 1
    for (int jj = 0; jj < 16; ++jj) {
        const int c = jj * 64 + l16 * 4;
        float ax = 0.f, ay = 0.f, az = 0.f, aw = 0.f;
        #pragma unroll
        for (int d = 0; d < DKH; d += 4) {
            const float4 q4 = *(const float4*)&q_lds[r][d];
            const float4 k0 = *(const float4*)(kbase + (size_t)(d + 0) * SEQ + c);
            const float4 k1 = *(const float4*)(kbase + (size_t)(d + 1) * SEQ + c);
            const float4 k2 = *(const float4*)(kbase + (size_t)(d + 2) * SEQ + c);
            const float4 k3 = *(const float4*)(kbase + (size_t)(d + 3) * SEQ + c);
            ax = fmaf(q4.w, k3.x, fmaf(q4.z, k2.x, fmaf(q4.y, k1.x, fmaf(q4.x, k0.x, ax))));
            ay = fmaf(q4.w, k3.y, fmaf(q4.z, k2.y, fmaf(q4.y, k1.y, fmaf(q4.x, k0.y, ay))));
            az = fmaf(q4.w, k3.z, fmaf(q4.z, k2.z, fmaf(q4.y, k1.z, fmaf(q4.x, k0.z, az))));
            aw = fmaf(q4.w, k3.w, fmaf(q4.z, k2.w, fmaf(q4.y, k1.w, fmaf(q4.x, k0.w, aw))));
        }
        const float4 p4 = *(const float4*)(prow + c);
        const float4 m4 = *(const float4*)(mrow + c);
        const unsigned int kp4 = *(const unsigned int*)(kpmb + c);
        float sx = fmaf(ax, scale, p4.x + m4.x);
        float sy = fmaf(ay, scale, p4.y + m4.y);
        float sz = fmaf(az, scale, p4.z + m4.z);
        float sw = fmaf(aw, scale, p4.w + m4.w);
        if (kp4 & 0x000000FFu) sx = -INFINITY;
        if (kp4 & 0x0000FF00u) sy = -INFINITY;
        if (kp4 & 0x00FF0000u) sz = -INFINITY;
        if (kp4 & 0xFF000000u) sw = -INFINITY;
        *(float4*)(srow + c) = make_float4(sx, sy, sz, sw);
        mx = fmaxf(mx, fmaxf(fmaxf(sx, sy), fmaxf(sz, sw)));
    }
    #pragma unroll
    for (int off = 1; off < 16; off <<= 1)
        mx = fmaxf(mx, __shfl_xor(mx, off, 64));

    // ---- phase 2: e = exp(s - mx) -> LDS (fp16), accumulate row sum ----
    float sum = 0.f;
    #pragma unroll 1
    for (int jj = 0; jj < 16; ++jj) {
        const int c = jj * 64 + l16 * 4;
        const float4 s4 = *(const float4*)(srow + c);   // L2-hot re-read
        const float e0 = __expf(s4.x - mx);
        const float e1 = __expf(s4.y - mx);
        const float e2 = __expf(s4.z - mx);
        const float e3 = __expf(s4.w - mx);
        sum += (e0 + e1) + (e2 + e3);
        h4v hv;
        hv[0] = (_Float16)e0; hv[1] = (_Float16)e1;
        hv[2] = (_Float16)e2; hv[3] = (_Float16)e3;
        *(h4v*)&a_lds[r][c] = hv;
    }
    #pragma unroll
    for (int off = 1; off < 16; off <<= 1)
        sum += __shfl_xor(sum, off, 64);
    const float inv = 1.0f / sum;

    // ---- phase 3: attn = e * inv -> global ----
    #pragma unroll 1
    for (int jj = 0; jj < 16; ++jj) {
        const int c = jj * 64 + l16 * 4;
        h4v hv = *(h4v*)&a_lds[r][c];
        *(float4*)(arow + c) = make_float4((float)hv[0] * inv, (float)hv[1] * inv,
                                           (float)hv[2] * inv, (float)hv[3] * inv);
    }
    __syncthreads();   // PV reads e written by other threads of the row group

    // ---- phase 4: out = inv * (e @ v) ----
    float ox = 0.f, oy = 0.f, oz = 0.f, ow = 0.f;
    const float* vbase = v + (size_t)bh * SEQ * DKH + l16 * 4;
    #pragma unroll 2
    for (int j = 0; j < SEQ; j += 8) {
        const h8v av = *(const h8v*)&a_lds[r][j];
        #pragma unroll
        for (int u = 0; u < 8; ++u) {
            const float a = (float)av[u];
            const float4 vv = *(const float4*)(vbase + (size_t)(j + u) * DKH);
            ox = fmaf(a, vv.x, ox);
            oy = fmaf(a, vv.y, oy);
            oz = fmaf(a, vv.z, oz);
            ow = fmaf(a, vv.w, ow);
        }
    }
    *(float4*)(out + ((size_t)bh * SEQ + row_g) * DKH + l16 * 4) =
        make_float4(ox * inv, oy * inv, oz * inv, ow * inv);
}

extern "C" void kernel_launch(void* const* d_in, const int* in_sizes, int n_in,
                              void* d_out, int out_size, void* d_ws, size_t ws_size,
                              hipStream_t stream) {
    const float* q    = (const float*)d_in[0];
    const float* k    = (const float*)d_in[1];   // [B,H,DK,S] (pre-transposed)
    const float* v    = (const float*)d_in[2];
    const float* prev = (const float*)d_in[3];
    const float* mask = (const float*)d_in[4];   // [1,S,S]
    const unsigned char* kpm = (const unsigned char*)d_in[5];  // [B,S] bool
    const float* scale = (const float*)d_in[6];

    float* out    = (float*)d_out;
    float* attn   = out  + (size_t)BSZ * NH * SEQ * DKH;
    float* scores = attn + (size_t)BSZ * NH * SEQ * SEQ;

    dim3 grid(SEQ / ROWS, BSZ * NH);
    fused_attn_kernel<<<grid, NTHR, 0, stream>>>(q, k, v, prev, mask, kpm, scale,
                                                 out, attn, scores);
}

// Round 2
// 266.762 us; speedup vs baseline: 8.0930x; 8.0930x over previous
//
#include <hip/hip_runtime.h>
#include <math.h>

#define SEQ 1024
#define DKH 64
#define QBLK 64
#define NTILE 16
#define KSTR 68   // bf16 elems per LDS row: 136B rows -> 8B aligned, ~4-way banks max

typedef short s8v __attribute__((ext_vector_type(8)));
typedef short s4v __attribute__((ext_vector_type(4)));
typedef float f4v __attribute__((ext_vector_type(4)));

__device__ __forceinline__ short f2bf(float f) {
    unsigned u = __builtin_bit_cast(unsigned, f);
    return (short)((u + 0x8000u) >> 16);   // round-half-up bf16
}

__device__ __forceinline__ s8v ld_frag(const unsigned short* p) {
    s4v a = *(const s4v*)(p);
    s4v b = *(const s4v*)(p + 4);
    s8v r;
    r[0]=a[0]; r[1]=a[1]; r[2]=a[2]; r[3]=a[3];
    r[4]=b[0]; r[5]=b[1]; r[6]=b[2]; r[7]=b[3];
    return r;
}

__global__ __launch_bounds__(256, 4)
void attn_fused(const float* __restrict__ q, const float* __restrict__ k,
                const float* __restrict__ v, const float* __restrict__ prev,
                const float* __restrict__ mask, const unsigned char* __restrict__ kpm,
                const float* __restrict__ scale_p,
                float* __restrict__ out, float* __restrict__ attn,
                float* __restrict__ scores)
{
    __shared__ unsigned short q_s[QBLK * KSTR];      // [qrow][dk]
    __shared__ unsigned short kv_s[64 * KSTR];       // pass1: [col][dk]; pass2: [d][c]
    __shared__ unsigned short e_s[4 * 16 * KSTR];    // per-wave [row][c]

    const int t   = threadIdx.x;
    const int w   = t >> 6;
    const int l   = t & 63;
    const int g   = l >> 4;
    const int c16 = l & 15;

    // XCD-aware swizzle: 16 consecutive blocks (one bh) land on one XCD
    const int wg  = blockIdx.x;
    const int swz = (wg & 7) * 128 + (wg >> 3);
    const int bh  = swz >> 4;
    const int rt  = swz & 15;
    const int b   = bh >> 4;

    const float scale = *scale_p;

    const float* qb = q    + ((size_t)bh * SEQ + rt * QBLK) * DKH;
    const float* kb = k    + (size_t)bh * DKH * SEQ;
    const float* vb = v    + (size_t)bh * SEQ * DKH;
    const float* pb = prev + ((size_t)bh * SEQ + rt * QBLK) * SEQ;
    const float* mb = mask + (size_t)(rt * QBLK) * SEQ;
    const unsigned char* kp = kpm + (size_t)b * SEQ;
    float* sb = scores + ((size_t)bh * SEQ + rt * QBLK) * SEQ;
    float* ab = attn   + ((size_t)bh * SEQ + rt * QBLK) * SEQ;
    float* ob = out    + ((size_t)bh * SEQ + rt * QBLK) * DKH;

    // ---- stage Q tile (f32 -> bf16, natural [row][dk]) ----
    {
        const int row = t >> 2, c0 = (t & 3) * 16;
        const float* src = qb + row * DKH + c0;
        #pragma unroll
        for (int j = 0; j < 4; ++j) {
            f4v f = *(const f4v*)(src + 4 * j);
            s4v h; h[0]=f2bf(f[0]); h[1]=f2bf(f[1]); h[2]=f2bf(f[2]); h[3]=f2bf(f[3]);
            *(s4v*)&q_s[row * KSTR + c0 + 4 * j] = h;
        }
    }
    __syncthreads();

    // hoist Q A-fragments (row = l&15 of wave's 16 rows, k = 8*(l>>4)+e)
    s8v aq[2];
    #pragma unroll
    for (int ks = 0; ks < 2; ++ks)
        aq[ks] = ld_frag(&q_s[(w * 16 + c16) * KSTR + ks * 32 + g * 8]);

    float m_r[4], l_r[4];
    #pragma unroll
    for (int r = 0; r < 4; ++r) { m_r[r] = -1e30f; l_r[r] = 0.f; }

    // ================ pass 1: scores + online softmax stats ================
    for (int ct = 0; ct < NTILE; ++ct) {
        __syncthreads();
        {   // stage K tile transposed: kv_s[col][dk], 4x4 register transpose
            const int a = t & 15, gg = t >> 4;
            const float* src = kb + (size_t)(4 * gg) * SEQ + ct * 64 + 4 * a;
            f4v r0 = *(const f4v*)(src);
            f4v r1 = *(const f4v*)(src + SEQ);
            f4v r2 = *(const f4v*)(src + 2 * SEQ);
            f4v r3 = *(const f4v*)(src + 3 * SEQ);
            #pragma unroll
            for (int j = 0; j < 4; ++j) {
                s4v h; h[0]=f2bf(r0[j]); h[1]=f2bf(r1[j]); h[2]=f2bf(r2[j]); h[3]=f2bf(r3[j]);
                *(s4v*)&kv_s[(4 * a + j) * KSTR + 4 * gg] = h;
            }
        }
        __syncthreads();

        f4v acc[4];
        #pragma unroll
        for (int s = 0; s < 4; ++s) acc[s] = 0;
        #pragma unroll
        for (int ks = 0; ks < 2; ++ks) {
            #pragma unroll
            for (int s = 0; s < 4; ++s) {
                s8v bk = ld_frag(&kv_s[(s * 16 + c16) * KSTR + ks * 32 + g * 8]);
                acc[s] = __builtin_amdgcn_mfma_f32_16x16x32_bf16(aq[ks], bk, acc[s], 0, 0, 0);
            }
        }

        const int colb = ct * 64;
        int kf[4];
        #pragma unroll
        for (int s = 0; s < 4; ++s) kf[s] = kp[colb + s * 16 + c16];

        #pragma unroll
        for (int r = 0; r < 4; ++r) {
            const int lrow = w * 16 + 4 * g + r;
            const float* prow = pb + (size_t)lrow * SEQ + colb + c16;
            const float* mrow = mb + (size_t)lrow * SEQ + colb + c16;
            float* srow = sb + (size_t)lrow * SEQ + colb + c16;
            float sv[4];
            #pragma unroll
            for (int s = 0; s < 4; ++s) {
                float x = fmaf(acc[s][r], scale, prow[s * 16] + mrow[s * 16]);
                sv[s] = kf[s] ? -INFINITY : x;
                srow[s * 16] = sv[s];
            }
            const float tm = fmaxf(fmaxf(sv[0], sv[1]), fmaxf(sv[2], sv[3]));
            const float mn = fmaxf(m_r[r], tm);
            const float lsum = __expf(sv[0] - mn) + __expf(sv[1] - mn)
                             + __expf(sv[2] - mn) + __expf(sv[3] - mn);
            l_r[r] = l_r[r] * __expf(m_r[r] - mn) + lsum;
            m_r[r] = mn;
        }
    }

    // LSE merge across the 16 lanes sharing a row group
    #pragma unroll
    for (int off = 1; off <= 8; off <<= 1) {
        #pragma unroll
        for (int r = 0; r < 4; ++r) {
            const float mo = __shfl_xor(m_r[r], off, 64);
            const float lo = __shfl_xor(l_r[r], off, 64);
            const float mn = fmaxf(m_r[r], mo);
            l_r[r] = l_r[r] * __expf(m_r[r] - mn) + lo * __expf(mo - mn);
            m_r[r] = mn;
        }
    }
    float inv_r[4];
    #pragma unroll
    for (int r = 0; r < 4; ++r) inv_r[r] = 1.0f / l_r[r];

    // per-lane row for coalesced score re-read (static-index selects, rule #20)
    const int lr = l >> 2, cq = l & 3;
    const int rsel = lr & 3;
    const float m_use   = rsel == 0 ? m_r[0]   : rsel == 1 ? m_r[1]   : rsel == 2 ? m_r[2]   : m_r[3];
    const float inv_use = rsel == 0 ? inv_r[0] : rsel == 1 ? inv_r[1] : rsel == 2 ? inv_r[2] : inv_r[3];

    // ================ pass 2: attn write + PV ================
    f4v oacc[4];
    #pragma unroll
    for (int d = 0; d < 4; ++d) oacc[d] = 0;

    for (int ct = 0; ct < NTILE; ++ct) {
        __syncthreads();
        {   // stage V tile transposed: kv_s[d][c]
            const int a = t & 15, gg = t >> 4;
            const float* src = vb + (size_t)(ct * 64 + 4 * gg) * DKH + 4 * a;
            f4v r0 = *(const f4v*)(src);
            f4v r1 = *(const f4v*)(src + DKH);
            f4v r2 = *(const f4v*)(src + 2 * DKH);
            f4v r3 = *(const f4v*)(src + 3 * DKH);
            #pragma unroll
            for (int j = 0; j < 4; ++j) {
                s4v h; h[0]=f2bf(r0[j]); h[1]=f2bf(r1[j]); h[2]=f2bf(r2[j]); h[3]=f2bf(r3[j]);
                *(s4v*)&kv_s[(4 * a + j) * KSTR + 4 * gg] = h;
            }
        }
        __syncthreads();

        {   // re-read scores (L2-hot), e = exp(s-m): attn out + e -> per-wave LDS
            const float* srow = sb + (size_t)(w * 16 + lr) * SEQ + ct * 64 + cq * 16;
            float* arow       = ab + (size_t)(w * 16 + lr) * SEQ + ct * 64 + cq * 16;
            unsigned short* erow = &e_s[(w * 16 + lr) * KSTR + cq * 16];
            #pragma unroll
            for (int j = 0; j < 4; ++j) {
                f4v s4 = *(const f4v*)(srow + 4 * j);
                const float e0 = __expf(s4[0] - m_use);
                const float e1 = __expf(s4[1] - m_use);
                const float e2 = __expf(s4[2] - m_use);
                const float e3 = __expf(s4[3] - m_use);
                f4v aw; aw[0]=e0*inv_use; aw[1]=e1*inv_use; aw[2]=e2*inv_use; aw[3]=e3*inv_use;
                *(f4v*)(arow + 4 * j) = aw;
                s4v h; h[0]=f2bf(e0); h[1]=f2bf(e1); h[2]=f2bf(e2); h[3]=f2bf(e3);
                *(s4v*)&erow[4 * j] = h;
            }
        }
        // PV MFMA: A = e (per-wave LDS, same-wave dep -> lgkmcnt only), B = V^T
        #pragma unroll
        for (int cs = 0; cs < 2; ++cs) {
            s8v ae = ld_frag(&e_s[(w * 16 + c16) * KSTR + cs * 32 + g * 8]);
            #pragma unroll
            for (int d = 0; d < 4; ++d) {
                s8v bv = ld_frag(&kv_s[(d * 16 + c16) * KSTR + cs * 32 + g * 8]);
                oacc[d] = __builtin_amdgcn_mfma_f32_16x16x32_bf16(ae, bv, oacc[d], 0, 0, 0);
            }
        }
    }

    #pragma unroll
    for (int d = 0; d < 4; ++d) {
        #pragma unroll
        for (int r = 0; r < 4; ++r) {
            ob[(size_t)(w * 16 + 4 * g + r) * DKH + d * 16 + c16] = oacc[d][r] * inv_r[r];
        }
    }
}

extern "C" void kernel_launch(void* const* d_in, const int* in_sizes, int n_in,
                              void* d_out, int out_size, void* d_ws, size_t ws_size,
                              hipStream_t stream) {
    const float* q    = (const float*)d_in[0];
    const float* k    = (const float*)d_in[1];   // [B,H,DK,S]
    const float* v    = (const float*)d_in[2];   // [B,H,S,DK]
    const float* prev = (const float*)d_in[3];
    const float* mask = (const float*)d_in[4];   // [1,S,S]
    const unsigned char* kpm = (const unsigned char*)d_in[5];  // [B,S] bool
    const float* scale = (const float*)d_in[6];

    float* out    = (float*)d_out;
    float* attn   = out  + (size_t)4 * 16 * SEQ * DKH;
    float* scores = attn + (size_t)4 * 16 * SEQ * SEQ;

    attn_fused<<<dim3(1024), dim3(256), 0, stream>>>(q, k, v, prev, mask, kpm, scale,
                                                     out, attn, scores);
}